// Round 12
// baseline (1779.937 us; speedup 1.0000x reference)
//
#include <hip/hip_runtime.h>
#include <math.h>

#define NAG 10
#define PP  65536
#define EE  64
#define INW 16
#define NBLK 768
#define NWAVES (NBLK*4)       // 3072 waves; each does 21-22 p's (grid-stride)
#define SU   68               // f32 stride of u rows in staging
#define SUBSZ (NAG*SU + 64 + 64)   // per-wave staging: u tile + h2 row + h0 row = 808 f32

typedef __attribute__((ext_vector_type(4))) short short4v;
typedef __attribute__((ext_vector_type(4))) float f32x4;

__device__ __forceinline__ short f2bf(float x){
    unsigned u = __float_as_uint(x);
    return (short)((u + 0x8000u) >> 16);     // round-nearest (ties away)
}

#define MFMA16(A,B,C) __builtin_amdgcn_mfma_f32_16x16x16bf16_1k((A),(B),(C),0,0,0)

// Fragment algebra (HW-verified rounds 5-11):
//   A-frag(16x16x16): lane holds A[row=l&15][k=(l>>4)*4+j]
//   B-frag:           lane holds B[k=(l>>4)*4+j][col=l&15]
//   D-frag:           lane holds D[row=(l>>4)*4+reg][col=l&15]
//   => D-frag of M reused as B-operand represents M; as A-operand represents M^T.

__global__ __launch_bounds__(256, 3) void mpnn_reg5(
    const float* __restrict__ inp,
    const float* __restrict__ W_enc, const float* __restrict__ b_enc,
    const float* __restrict__ W_goal, const float* __restrict__ b_goal,
    const float* __restrict__ Wq, const float* __restrict__ Wk,
    const float* __restrict__ Wv, const float* __restrict__ Wo,
    const float* __restrict__ W_upd, const float* __restrict__ b_upd,
    float* __restrict__ out)
{
    // pool layout:
    //   region A [0,16640): init WkT (64x65 f32) / Wc (64x64 f32); after init:
    //       wvl [0,8192)  = Wvc  B-frags, uint2[16][64]
    //       wul [8192,16384) = Wu_top B-frags, uint2[16][64]
    //   region B [16640, 16640+4*3232): per-wave staging (wave-private)
    __shared__ __align__(16) char pool[16640 + 4*SUBSZ*4];

    const int tid  = threadIdx.x;
    const int w    = tid >> 6;
    const int l    = tid & 63;
    const int lrow = l & 15;
    const int lk   = l >> 4;

    float*   const ldsA = (float*)pool;
    short4v* const wvl  = (short4v*)pool;            // [16][64]
    short4v* const wul  = (short4v*)(pool + 8192);   // [16][64]
    float*   const stg  = (float*)(pool + 16640) + w*SUBSZ;
    float*   const h2r  = stg + NAG*SU;
    float*   const h0r  = h2r + 64;

    // ================= init (barriers only here) =================
    // WkT staging (coalesced read, padded write)
    for (int i = tid; i < EE*EE; i += 256)
        ldsA[(i & 63)*65 + (i >> 6)] = Wk[i];
    __syncthreads();

    // fqkA[o][i]: A-frag of Wqk^T = (Wq@Wk^T * 1/8)^T  (stays in registers)
    short4v fqkA[4][4];
    #pragma unroll
    for (int i = 0; i < 4; ++i)
      #pragma unroll
      for (int j = 0; j < 4; ++j) {
        const int ein = 16*i + lk*4 + j;
        float s[4] = {0.f,0.f,0.f,0.f};
        for (int t = 0; t < EE; ++t) {
            const float wq = Wq[ein*EE + t];
            #pragma unroll
            for (int o = 0; o < 4; ++o)
                s[o] = fmaf(wq, ldsA[t*65 + 16*o + lrow], s[o]);
        }
        #pragma unroll
        for (int o = 0; o < 4; ++o)
            fqkA[o][i][j] = f2bf(s[o] * 0.125f);
      }
    __syncthreads();

    // Wc = Wo @ W_upd[64:128]
    for (int i = tid; i < EE*EE; i += 256) {
        const int r = i >> 6, c = i & 63;
        float s = 0.f;
        #pragma unroll 8
        for (int d = 0; d < EE; ++d)
            s = fmaf(Wo[r*EE + d], W_upd[(EE + d)*EE + c], s);
        ldsA[r*EE + c] = s;
    }
    __syncthreads();

    // Wvc = Wv @ Wc -> B-frags into temp regs (region A still holds Wc)
    short4v tvc[4][4];
    #pragma unroll
    for (int i = 0; i < 4; ++i)
      #pragma unroll
      for (int j = 0; j < 4; ++j) {
        const int ein = 16*i + lk*4 + j;
        float s[4] = {0.f,0.f,0.f,0.f};
        for (int d = 0; d < EE; ++d) {
            const float wv = Wv[ein*EE + d];
            #pragma unroll
            for (int t = 0; t < 4; ++t)
                s[t] = fmaf(wv, ldsA[d*EE + 16*t + lrow], s[t]);
        }
        #pragma unroll
        for (int t = 0; t < 4; ++t)
            tvc[i][t][j] = f2bf(s[t]);
      }
    __syncthreads();   // Wc reads done -> region A reusable

    // write Wvc + Wu_top B-frags to LDS (read-only afterwards)
    #pragma unroll
    for (int i = 0; i < 4; ++i)
      #pragma unroll
      for (int t = 0; t < 4; ++t) {
        if (w == 0) wvl[(i*4 + t)*64 + l] = tvc[i][t];
        if (w == 1) {
            short4v fu;
            #pragma unroll
            for (int j = 0; j < 4; ++j)
                fu[j] = f2bf(W_upd[(16*i + lk*4 + j)*EE + 16*t + lrow]);
            wul[(i*4 + t)*64 + l] = fu;
        }
      }
    __syncthreads();   // weights visible to all waves; no more barriers

    // fencA[i]: A-frag of Wenc^T; row 14 = 0 (goal slot), row 15 = b_enc (bias fold)
    short4v fencA[4];
    #pragma unroll
    for (int i = 0; i < 4; ++i)
      #pragma unroll
      for (int j = 0; j < 4; ++j) {
        const int d = lk*4 + j;
        fencA[i][j] = (d < 14) ? f2bf(W_enc[d*EE + 16*i + lrow])
                    : (d == 15 ? f2bf(b_enc[16*i + lrow]) : (short)0);
      }

    float bupd4[4], wg0v[4], wg1v[4], bgv[4];
    #pragma unroll
    for (int t = 0; t < 4; ++t) {
        bupd4[t] = b_upd[16*t + lrow];
        wg0v[t]  = W_goal[16*t + lrow];
        wg1v[t]  = W_goal[EE + 16*t + lrow];
        bgv[t]   = b_goal[16*t + lrow];
    }

    // ================= main loop: one wave = one p; no barriers =================
    const int gwave = blockIdx.x*4 + w;
    const int arow  = (lrow < NAG) ? lrow : 0;   // clamp pad-agents (valid reads)
    const float* xptr = inp + (size_t)arow*PP*INW + lk*4;

    f32x4 xin = *(const f32x4*)(xptr + (size_t)gwave*INW);

    for (int p = gwave; p < PP; p += NWAVES) {
        const f32x4 xcur = xin;
        if (p + NWAVES < PP)
            xin = *(const f32x4*)(xptr + (size_t)(p + NWAVES)*INW);

        // goal scalars: lane 48 (lk=3,lrow=0) holds X[0][12..15] -> elems 2,3
        const float g0 = __shfl(xcur[2], 48, 64);
        const float g1 = __shfl(xcur[3], 48, 64);

        // X as B-frag of X^T; d=15 column forced to 1.0 (bias fold)
        short4v xb;
        #pragma unroll
        for (int j = 0; j < 4; ++j) xb[j] = f2bf(xcur[j]);
        if (lk == 3) xb[3] = (short)0x3F80;

        // ---- h^T slices (bias via MFMA), relu
        f32x4 hT[4];
        #pragma unroll
        for (int i = 0; i < 4; ++i) {
            f32x4 zz = {0.f,0.f,0.f,0.f};
            hT[i] = MFMA16(fencA[i], xb, zz);
            #pragma unroll
            for (int r = 0; r < 4; ++r)
                hT[i][r] = fmaxf(hT[i][r], 0.f);
        }

        // h0 row: lanes lrow==0 hold h[agent0][16i+lk*4+r] -> direct b128 writes
        if (lrow == 0) {
            #pragma unroll
            for (int i = 0; i < 4; ++i)
                *(f32x4*)&h0r[16*i + lk*4] = hT[i];
        }
        // h2 row: e = 16t+lrow, one writer set (lk==0)
        if (lk == 0) {
            #pragma unroll
            for (int t = 0; t < 4; ++t)
                h2r[16*t + lrow] =
                    fmaxf(fmaf(g0, wg0v[t], fmaf(g1, wg1v[t], bgv[t])), 0.f);
        }

        short4v hb[4];
        #pragma unroll
        for (int i = 0; i < 4; ++i)
            #pragma unroll
            for (int j = 0; j < 4; ++j) hb[i][j] = f2bf(hT[i][j]);

        // ---- G^T slices
        short4v gb[4];
        #pragma unroll
        for (int o = 0; o < 4; ++o) {
            f32x4 acc = {0.f,0.f,0.f,0.f};
            #pragma unroll
            for (int i = 0; i < 4; ++i)
                acc = MFMA16(fqkA[o][i], hb[i], acc);
            #pragma unroll
            for (int j = 0; j < 4; ++j) gb[o][j] = f2bf(acc[j]);
        }

        // ---- S^T; lane holds S^T[k=lk*4+j][q=lrow]
        f32x4 st = {0.f,0.f,0.f,0.f};
        #pragma unroll
        for (int i = 0; i < 4; ++i)
            st = MFMA16(hb[i], gb[i], st);

        // ---- masked softmax (in-register)
        float c4[4]; float mx4 = -1e30f;
        #pragma unroll
        for (int j = 0; j < 4; ++j) {
            const int k = lk*4 + j;
            const bool valid = (lrow < NAG) && (k < NAG) && (k != lrow) && (k != 0);
            c4[j] = valid ? st[j] : -1e30f;
            mx4 = fmaxf(mx4, c4[j]);
        }
        float mx = fmaxf(mx4, __shfl_xor(mx4, 16, 64));
        mx = fmaxf(mx, __shfl_xor(mx, 32, 64));
        float e4[4], ssum = 0.f;
        #pragma unroll
        for (int j = 0; j < 4; ++j) { e4[j] = __expf(c4[j] - mx); ssum += e4[j]; }
        ssum += __shfl_xor(ssum, 16, 64);
        ssum += __shfl_xor(ssum, 32, 64);
        const float inv = 1.f / ssum;
        short4v pa;
        #pragma unroll
        for (int j = 0; j < 4; ++j) pa[j] = f2bf(e4[j] * inv);

        // ---- Z = h @ Wvc  (B-frags streamed from LDS)
        short4v zbv[4];
        #pragma unroll
        for (int t = 0; t < 4; ++t) {
            f32x4 acc = {0.f,0.f,0.f,0.f};
            #pragma unroll
            for (int i = 0; i < 4; ++i)
                acc = MFMA16(hb[i], wvl[(i*4 + t)*64 + l], acc);
            #pragma unroll
            for (int j = 0; j < 4; ++j) zbv[t][j] = f2bf(acc[j]);
        }

        // ---- u = relu(P@Z + h@Wu_top + b_upd) -> wave-private staging
        #pragma unroll
        for (int t = 0; t < 4; ++t) {
            f32x4 acc = {0.f,0.f,0.f,0.f};
            acc = MFMA16(pa, zbv[t], acc);
            #pragma unroll
            for (int i = 0; i < 4; ++i)
                acc = MFMA16(hb[i], wul[(i*4 + t)*64 + l], acc);
            #pragma unroll
            for (int r = 0; r < 4; ++r) {
                const int agent = lk*4 + r;
                if (agent < NAG)
                    stg[agent*SU + 16*t + lrow] = fmaxf(acc[r] + bupd4[t], 0.f);
            }
        }
        // wave-internal ds_write -> ds_read in-order (compiler lgkmcnt)

        // ---- stores: 5 nt f32x4 instrs; each covers 2 rows x 512 B full lines
        #pragma unroll
        for (int c = 0; c < 5; ++c) {
            const int flat = c*64 + l;
            const int row  = flat >> 5;          // 0..9 (agent)
            const int c4i  = flat & 31;          // float4 idx within 128 cols
            const float* sp = (c4i < 16)
                ? &stg[row*SU + c4i*4]
                : ((row == 0) ? &h2r[(c4i-16)*4] : &h0r[(c4i-16)*4]);
            const f32x4 v = *reinterpret_cast<const f32x4*>(sp);
            float* dst = out + ((size_t)row*PP + (size_t)p)*128 + c4i*4;
            __builtin_nontemporal_store(v, (f32x4*)dst);
        }
    }
}

extern "C" void kernel_launch(void* const* d_in, const int* in_sizes, int n_in,
                              void* d_out, int out_size, void* d_ws, size_t ws_size,
                              hipStream_t stream) {
    const float* inp    = (const float*)d_in[0];
    const float* W_enc  = (const float*)d_in[1];
    const float* b_enc  = (const float*)d_in[2];
    const float* W_goal = (const float*)d_in[3];
    const float* b_goal = (const float*)d_in[4];
    const float* Wq     = (const float*)d_in[5];
    const float* Wk     = (const float*)d_in[6];
    const float* Wv     = (const float*)d_in[7];
    const float* Wo     = (const float*)d_in[8];
    const float* W_upd  = (const float*)d_in[9];
    const float* b_upd  = (const float*)d_in[10];

    hipLaunchKernelGGL(mpnn_reg5, dim3(NBLK), dim3(256), 0, stream,
                       inp, W_enc, b_enc, W_goal, b_goal,
                       Wq, Wk, Wv, Wo, W_upd, b_upd, (float*)d_out);
}